// Round 6
// baseline (129.943 us; speedup 1.0000x reference)
//
#include <hip/hip_runtime.h>
#include <hip/hip_bf16.h>

// RestrictedNN DAG. Round 6: TB=8, no x LDS stage (direct global reads with
// 4-lane same-line merge), lazy W1t/W2t fragment loads -> ~6 blocks/CU.
// B=4096, L0=512 leaves (G=8,H=16), L1=64, L2=8 (FAN=8), root 128->16.

#define TB 8
#define H0S 1032     // ushorts per h0 row (1024+8): rows 16B-aligned; 516dw==4 mod 32
#define H1S 136      // ushorts per h1 row (128+8): rows 16B-aligned

typedef __attribute__((ext_vector_type(8))) short short8;
typedef __attribute__((ext_vector_type(4))) float floatx4;

__device__ __forceinline__ float sigf(float v) {
    return __builtin_amdgcn_rcpf(1.0f + __expf(-v));
}
__device__ __forceinline__ unsigned int f2bf_u32(float f) {   // RNE, bf16 in low 16
    unsigned int u = __builtin_bit_cast(unsigned int, f);
    return (u + 0x7fffu + ((u >> 16) & 1u)) >> 16;
}
__device__ __forceinline__ unsigned short f2bf(float f) {
    return (unsigned short)f2bf_u32(f);
}
__device__ __forceinline__ unsigned int f2bf2(float lo, float hi) {
    return f2bf_u32(lo) | (f2bf_u32(hi) << 16);
}

// ---- prep: transpose W1/W2 per module to bf16 [h][k] fragment layout ----
__global__ __launch_bounds__(256) void k_prep(
    const float* __restrict__ W1, const float* __restrict__ W2,
    unsigned short* __restrict__ W1t, unsigned short* __restrict__ W2t)
{
    __shared__ float wl[128 * 17];
    const int mb = blockIdx.x;              // 0..63 -> W1, 64..71 -> W2
    const float* src = (mb < 64) ? (W1 + (size_t)mb * 2048)
                                 : (W2 + (size_t)(mb - 64) * 2048);
    unsigned short* dst = (mb < 64) ? (W1t + (size_t)mb * 2048)
                                    : (W2t + (size_t)(mb - 64) * 2048);
    const int tid = threadIdx.x;
#pragma unroll
    for (int i = 0; i < 8; ++i) {
        const int idx = tid + i * 256;      // [k][h] in, coalesced
        wl[(idx >> 4) * 17 + (idx & 15)] = src[idx];
    }
    __syncthreads();
#pragma unroll
    for (int i = 0; i < 4; ++i) {
        const int u  = tid + i * 256;       // uint index over [h][k] bf16 out
        const int h  = u >> 6;
        const int k  = (u & 63) * 2;
        ((unsigned int*)dst)[u] = f2bf2(wl[k * 17 + h], wl[(k + 1) * 17 + h]);
    }
}

__global__ __launch_bounds__(256) void k_tree(
    const float* __restrict__ x, const float* __restrict__ Wg,
    const float* __restrict__ bg, const float* __restrict__ W0,
    const unsigned short* __restrict__ W1t, const unsigned short* __restrict__ W2t,
    float* __restrict__ h2ws)
{
    __shared__ __align__(16) unsigned short h0s[TB * H0S];   // 16512 B
    __shared__ __align__(16) unsigned short h1s[TB * H1S];   //  2176 B (18.7 KB total)

    const int tid  = threadIdx.x;
    const int s    = blockIdx.x & 7;          // subtree == h2 module (== XCD slice)
    const int b0   = (blockIdx.x >> 3) * TB;  // batch tile base
    const int lane = tid & 63;
    const int wv   = tid >> 6;
    const int m_l  = tid >> 2;                // local leaf module 0..63
    const int hq   = tid & 3;                 // h quad
    const int m    = s * 64 + m_l;

    // ---------- phase-A weights (lane-contiguous W0: 4 lanes = one 64B line) ----
    float4 w0r[8];
#pragma unroll
    for (int g = 0; g < 8; ++g)
        w0r[g] = *(const float4*)(W0 + (size_t)m * 128 + g * 16 + hq * 4);
    const float4 wg0 = *(const float4*)(Wg + m * 8);
    const float4 wg1 = *(const float4*)(Wg + m * 8 + 4);
    const float4 bg0 = *(const float4*)(bg + m * 8);
    const float4 bg1 = *(const float4*)(bg + m * 8 + 4);

    // ---------- phase A: gene + h0, x read direct from global ----------
    // hq lanes (0..3) share each 32B x chunk -> merged same-line requests.
    {
        const float* xb = x + (size_t)b0 * 4096 + s * 512 + m_l * 8;
        unsigned short* h0base = &h0s[m_l * 16 + hq * 4];
#pragma unroll
        for (int b = 0; b < TB; ++b) {
            const float4 xv0 = *(const float4*)(xb + (size_t)b * 4096);
            const float4 xv1 = *(const float4*)(xb + (size_t)b * 4096 + 4);
            float gene[8];
            gene[0] = fmaf(xv0.x, wg0.x, bg0.x);
            gene[1] = fmaf(xv0.y, wg0.y, bg0.y);
            gene[2] = fmaf(xv0.z, wg0.z, bg0.z);
            gene[3] = fmaf(xv0.w, wg0.w, bg0.w);
            gene[4] = fmaf(xv1.x, wg1.x, bg1.x);
            gene[5] = fmaf(xv1.y, wg1.y, bg1.y);
            gene[6] = fmaf(xv1.z, wg1.z, bg1.z);
            gene[7] = fmaf(xv1.w, wg1.w, bg1.w);
            float a0 = 0.f, a1 = 0.f, a2 = 0.f, a3 = 0.f;
#pragma unroll
            for (int g = 0; g < 8; ++g) {
                a0 = fmaf(gene[g], w0r[g].x, a0);
                a1 = fmaf(gene[g], w0r[g].y, a1);
                a2 = fmaf(gene[g], w0r[g].z, a2);
                a3 = fmaf(gene[g], w0r[g].w, a3);
            }
            *(uint2*)(h0base + b * H0S) =
                make_uint2(f2bf2(sigf(a0), sigf(a1)), f2bf2(sigf(a2), sigf(a3)));
        }
    }
    __syncthreads();

    // ---------- phase B: h1 MFMA. wave wv -> modules {2wv, 2wv+1} ----------
    // TB=8 < M=16: A rows 8..15 duplicate rows 0..7 (n&7); C rows >=8 discarded.
    const int n = lane & 15, q = lane >> 4;
    {
#pragma unroll
        for (int jj = 0; jj < 2; ++jj) {
            const int j = wv * 2 + jj;
            const unsigned short* w1m =
                W1t + ((size_t)(s * 8 + j) * 16 + n) * 128 + q * 8;
            const unsigned short* am = &h0s[(n & 7) * H0S + j * 128 + q * 8];
            floatx4 acc = {0.f, 0.f, 0.f, 0.f};
#pragma unroll
            for (int ks = 0; ks < 4; ++ks) {
                const short8 av = *(const short8*)(am + ks * 32);
                const short8 bv = *(const short8*)(w1m + ks * 32);
                acc = __builtin_amdgcn_mfma_f32_16x16x32_bf16(av, bv, acc, 0, 0, 0);
            }
            if (q < 2) {
#pragma unroll
                for (int r = 0; r < 4; ++r)
                    h1s[(q * 4 + r) * H1S + j * 16 + n] = f2bf(sigf(acc[r]));
            }
        }
    }
    __syncthreads();

    // ---------- phase C: h2 MFMA (module s), wave 0 only ----------
    if (wv == 0) {
        const unsigned short* w2m = W2t + ((size_t)s * 16 + n) * 128 + q * 8;
        const unsigned short* am = &h1s[(n & 7) * H1S + q * 8];
        floatx4 acc = {0.f, 0.f, 0.f, 0.f};
#pragma unroll
        for (int ks = 0; ks < 4; ++ks) {
            const short8 av = *(const short8*)(am + ks * 32);
            const short8 bv = *(const short8*)(w2m + ks * 32);
            acc = __builtin_amdgcn_mfma_f32_16x16x32_bf16(av, bv, acc, 0, 0, 0);
        }
        if (q < 2) {
#pragma unroll
            for (int r = 0; r < 4; ++r)
                h2ws[(size_t)(b0 + q * 4 + r) * 128 + s * 16 + n] = sigf(acc[r]);
        }
    }
}

// ---------- kernel: root (128->16, sigmoid) + final dot(16) ----------
__global__ __launch_bounds__(128) void k_root(
    const float* __restrict__ h2ws, const float* __restrict__ W3,
    const float* __restrict__ Wf, float* __restrict__ out)
{
    __shared__ float w3s[2048];
    __shared__ float wfs[16];
    const int tid = threadIdx.x;
#pragma unroll
    for (int t = 0; t < 16; ++t) w3s[tid + t * 128] = W3[tid + t * 128];
    if (tid < 16) wfs[tid] = Wf[tid];
    __syncthreads();

    const int h = tid & 15;
    const int b = blockIdx.x * 8 + (tid >> 4);
    const float4* hp = (const float4*)(h2ws + (size_t)b * 128);
    float acc = 0.f;
#pragma unroll
    for (int k4 = 0; k4 < 32; ++k4) {
        const float4 hv = hp[k4];
        acc = fmaf(hv.x, w3s[(k4 * 4 + 0) * 16 + h], acc);
        acc = fmaf(hv.y, w3s[(k4 * 4 + 1) * 16 + h], acc);
        acc = fmaf(hv.z, w3s[(k4 * 4 + 2) * 16 + h], acc);
        acc = fmaf(hv.w, w3s[(k4 * 4 + 3) * 16 + h], acc);
    }
    float v = sigf(acc) * wfs[h];
    v += __shfl_down(v, 8, 16);
    v += __shfl_down(v, 4, 16);
    v += __shfl_down(v, 2, 16);
    v += __shfl_down(v, 1, 16);
    if (h == 0) out[b] = v;
}

extern "C" void kernel_launch(void* const* d_in, const int* in_sizes, int n_in,
                              void* d_out, int out_size, void* d_ws, size_t ws_size,
                              hipStream_t stream) {
    const float* x  = (const float*)d_in[0];
    const float* Wg = (const float*)d_in[1];
    const float* bg = (const float*)d_in[2];
    const float* W0 = (const float*)d_in[3];
    const float* W1 = (const float*)d_in[4];
    const float* W2 = (const float*)d_in[5];
    const float* W3 = (const float*)d_in[6];
    const float* Wf = (const float*)d_in[7];
    float* out = (float*)d_out;

    float* h2 = (float*)d_ws;                                   // 4096*128 f32 = 2 MB
    unsigned short* W1t = (unsigned short*)((char*)d_ws + (size_t)2 * 1024 * 1024); // 256 KB
    unsigned short* W2t = W1t + (size_t)64 * 2048;                                  // 32 KB

    k_prep<<<dim3(72), dim3(256), 0, stream>>>(W1, W2, W1t, W2t);
    k_tree<<<dim3((4096 / TB) * 8), dim3(256), 0, stream>>>(x, Wg, bg, W0, W1t, W2t, h2);
    k_root<<<dim3(4096 / 8), dim3(128), 0, stream>>>(h2, W3, Wf, out);
}

// Round 7
// 125.885 us; speedup vs baseline: 1.0322x; 1.0322x over previous
//
#include <hip/hip_runtime.h>
#include <hip/hip_bf16.h>

// RestrictedNN DAG. Round 7: async x staging via global_load_lds (width=16).
//  - x tile (TB=8 rows x 512 f32 = 16 KB) DMA'd to LDS at kernel entry: no
//    VGPR cost, 4 issues all in flight; weight prefetch under the DMA shadow.
//  - phase A reads x from LDS (4-lane broadcast per 16B chunk).
//  - phases B (h1 MFMA) / C (h2 MFMA) unchanged from round 6.
// B=4096, L0=512 leaves (G=8,H=16), L1=64, L2=8 (FAN=8), root 128->16.

#define TB 8
#define H0S 1032     // ushorts per h0 row (1024+8): rows 16B-aligned; 516dw==4 mod 32
#define H1S 136      // ushorts per h1 row (128+8): rows 16B-aligned

typedef __attribute__((ext_vector_type(8))) short short8;
typedef __attribute__((ext_vector_type(4))) float floatx4;
typedef __attribute__((address_space(3))) void lds_void;
typedef const __attribute__((address_space(1))) void gbl_void;

__device__ __forceinline__ float sigf(float v) {
    return __builtin_amdgcn_rcpf(1.0f + __expf(-v));
}
__device__ __forceinline__ unsigned int f2bf_u32(float f) {   // RNE, bf16 in low 16
    unsigned int u = __builtin_bit_cast(unsigned int, f);
    return (u + 0x7fffu + ((u >> 16) & 1u)) >> 16;
}
__device__ __forceinline__ unsigned short f2bf(float f) {
    return (unsigned short)f2bf_u32(f);
}
__device__ __forceinline__ unsigned int f2bf2(float lo, float hi) {
    return f2bf_u32(lo) | (f2bf_u32(hi) << 16);
}

// ---- prep: transpose W1/W2 per module to bf16 [h][k] fragment layout ----
__global__ __launch_bounds__(256) void k_prep(
    const float* __restrict__ W1, const float* __restrict__ W2,
    unsigned short* __restrict__ W1t, unsigned short* __restrict__ W2t)
{
    __shared__ float wl[128 * 17];
    const int mb = blockIdx.x;              // 0..63 -> W1, 64..71 -> W2
    const float* src = (mb < 64) ? (W1 + (size_t)mb * 2048)
                                 : (W2 + (size_t)(mb - 64) * 2048);
    unsigned short* dst = (mb < 64) ? (W1t + (size_t)mb * 2048)
                                    : (W2t + (size_t)(mb - 64) * 2048);
    const int tid = threadIdx.x;
#pragma unroll
    for (int i = 0; i < 8; ++i) {
        const int idx = tid + i * 256;      // [k][h] in, coalesced
        wl[(idx >> 4) * 17 + (idx & 15)] = src[idx];
    }
    __syncthreads();
#pragma unroll
    for (int i = 0; i < 4; ++i) {
        const int u  = tid + i * 256;       // uint index over [h][k] bf16 out
        const int h  = u >> 6;
        const int k  = (u & 63) * 2;
        ((unsigned int*)dst)[u] = f2bf2(wl[k * 17 + h], wl[(k + 1) * 17 + h]);
    }
}

__global__ __launch_bounds__(256) void k_tree(
    const float* __restrict__ x, const float* __restrict__ Wg,
    const float* __restrict__ bg, const float* __restrict__ W0,
    const unsigned short* __restrict__ W1t, const unsigned short* __restrict__ W2t,
    float* __restrict__ h2ws)
{
    __shared__ __align__(16) float xs[TB * 512];             // 16384 B, NO pad (DMA layout)
    __shared__ __align__(16) unsigned short h0s[TB * H0S];   // 16512 B
    __shared__ __align__(16) unsigned short h1s[TB * H1S];   //  2176 B (35 KB total)

    const int tid  = threadIdx.x;
    const int s    = blockIdx.x & 7;          // subtree == h2 module (== XCD slice)
    const int b0   = (blockIdx.x >> 3) * TB;  // batch tile base
    const int lane = tid & 63;
    const int wv   = tid >> 6;
    const int m_l  = tid >> 2;                // local leaf module 0..63
    const int hq   = tid & 3;                 // h quad
    const int m    = s * 64 + m_l;

    // ---------- async DMA: x tile -> LDS (4 issues, all outstanding) ----------
    // linear float4 index i = (t*4 + wv)*64 + lane over the 8x512 tile;
    // lane writes ldsbase + lane*16, so LDS layout == linear tile layout.
    {
        const float* xbase = x + (size_t)b0 * 4096 + s * 512;
#pragma unroll
        for (int t = 0; t < 4; ++t) {
            const int i    = (t * 4 + wv) * 64 + lane;   // float4 units
            const int row  = i >> 7;
            const int colf = (i & 127) * 4;
            gbl_void* gp = (gbl_void*)(xbase + (size_t)row * 4096 + colf);
            lds_void* lp = (lds_void*)((char*)xs + (size_t)(t * 4 + wv) * 1024);
            __builtin_amdgcn_global_load_lds(gp, lp, 16, 0, 0);
        }
    }

    // ---------- weight prefetch under the DMA shadow ----------
    float4 w0r[8];
#pragma unroll
    for (int g = 0; g < 8; ++g)
        w0r[g] = *(const float4*)(W0 + (size_t)m * 128 + g * 16 + hq * 4);
    const float4 wg0 = *(const float4*)(Wg + m * 8);
    const float4 wg1 = *(const float4*)(Wg + m * 8 + 4);
    const float4 bg0 = *(const float4*)(bg + m * 8);
    const float4 bg1 = *(const float4*)(bg + m * 8 + 4);
    __syncthreads();   // drains DMA (vmcnt) + orders LDS

    // ---------- phase A: gene + h0 from LDS x ----------
    // hq lanes 0..3 read the same 32B -> LDS broadcast (free).
    {
        const float* xb = &xs[m_l * 8];
        unsigned short* h0base = &h0s[m_l * 16 + hq * 4];
#pragma unroll
        for (int b = 0; b < TB; ++b) {
            const float4 xv0 = *(const float4*)(xb + b * 512);
            const float4 xv1 = *(const float4*)(xb + b * 512 + 4);
            float gene[8];
            gene[0] = fmaf(xv0.x, wg0.x, bg0.x);
            gene[1] = fmaf(xv0.y, wg0.y, bg0.y);
            gene[2] = fmaf(xv0.z, wg0.z, bg0.z);
            gene[3] = fmaf(xv0.w, wg0.w, bg0.w);
            gene[4] = fmaf(xv1.x, wg1.x, bg1.x);
            gene[5] = fmaf(xv1.y, wg1.y, bg1.y);
            gene[6] = fmaf(xv1.z, wg1.z, bg1.z);
            gene[7] = fmaf(xv1.w, wg1.w, bg1.w);
            float a0 = 0.f, a1 = 0.f, a2 = 0.f, a3 = 0.f;
#pragma unroll
            for (int g = 0; g < 8; ++g) {
                a0 = fmaf(gene[g], w0r[g].x, a0);
                a1 = fmaf(gene[g], w0r[g].y, a1);
                a2 = fmaf(gene[g], w0r[g].z, a2);
                a3 = fmaf(gene[g], w0r[g].w, a3);
            }
            *(uint2*)(h0base + b * H0S) =
                make_uint2(f2bf2(sigf(a0), sigf(a1)), f2bf2(sigf(a2), sigf(a3)));
        }
    }
    __syncthreads();

    // ---------- phase B: h1 MFMA. wave wv -> modules {2wv, 2wv+1} ----------
    // TB=8 < M=16: A rows 8..15 duplicate rows 0..7 (n&7); C rows >=8 discarded.
    const int n = lane & 15, q = lane >> 4;
    {
#pragma unroll
        for (int jj = 0; jj < 2; ++jj) {
            const int j = wv * 2 + jj;
            const unsigned short* w1m =
                W1t + ((size_t)(s * 8 + j) * 16 + n) * 128 + q * 8;
            const unsigned short* am = &h0s[(n & 7) * H0S + j * 128 + q * 8];
            floatx4 acc = {0.f, 0.f, 0.f, 0.f};
#pragma unroll
            for (int ks = 0; ks < 4; ++ks) {
                const short8 av = *(const short8*)(am + ks * 32);
                const short8 bv = *(const short8*)(w1m + ks * 32);
                acc = __builtin_amdgcn_mfma_f32_16x16x32_bf16(av, bv, acc, 0, 0, 0);
            }
            if (q < 2) {
#pragma unroll
                for (int r = 0; r < 4; ++r)
                    h1s[(q * 4 + r) * H1S + j * 16 + n] = f2bf(sigf(acc[r]));
            }
        }
    }
    __syncthreads();

    // ---------- phase C: h2 MFMA (module s), wave 0 only ----------
    if (wv == 0) {
        const unsigned short* w2m = W2t + ((size_t)s * 16 + n) * 128 + q * 8;
        const unsigned short* am = &h1s[(n & 7) * H1S + q * 8];
        floatx4 acc = {0.f, 0.f, 0.f, 0.f};
#pragma unroll
        for (int ks = 0; ks < 4; ++ks) {
            const short8 av = *(const short8*)(am + ks * 32);
            const short8 bv = *(const short8*)(w2m + ks * 32);
            acc = __builtin_amdgcn_mfma_f32_16x16x32_bf16(av, bv, acc, 0, 0, 0);
        }
        if (q < 2) {
#pragma unroll
            for (int r = 0; r < 4; ++r)
                h2ws[(size_t)(b0 + q * 4 + r) * 128 + s * 16 + n] = sigf(acc[r]);
        }
    }
}

// ---------- kernel: root (128->16, sigmoid) + final dot(16) ----------
__global__ __launch_bounds__(128) void k_root(
    const float* __restrict__ h2ws, const float* __restrict__ W3,
    const float* __restrict__ Wf, float* __restrict__ out)
{
    __shared__ float w3s[2048];
    __shared__ float wfs[16];
    const int tid = threadIdx.x;
#pragma unroll
    for (int t = 0; t < 16; ++t) w3s[tid + t * 128] = W3[tid + t * 128];
    if (tid < 16) wfs[tid] = Wf[tid];
    __syncthreads();

    const int h = tid & 15;
    const int b = blockIdx.x * 8 + (tid >> 4);
    const float4* hp = (const float4*)(h2ws + (size_t)b * 128);
    float acc = 0.f;
#pragma unroll
    for (int k4 = 0; k4 < 32; ++k4) {
        const float4 hv = hp[k4];
        acc = fmaf(hv.x, w3s[(k4 * 4 + 0) * 16 + h], acc);
        acc = fmaf(hv.y, w3s[(k4 * 4 + 1) * 16 + h], acc);
        acc = fmaf(hv.z, w3s[(k4 * 4 + 2) * 16 + h], acc);
        acc = fmaf(hv.w, w3s[(k4 * 4 + 3) * 16 + h], acc);
    }
    float v = sigf(acc) * wfs[h];
    v += __shfl_down(v, 8, 16);
    v += __shfl_down(v, 4, 16);
    v += __shfl_down(v, 2, 16);
    v += __shfl_down(v, 1, 16);
    if (h == 0) out[b] = v;
}

extern "C" void kernel_launch(void* const* d_in, const int* in_sizes, int n_in,
                              void* d_out, int out_size, void* d_ws, size_t ws_size,
                              hipStream_t stream) {
    const float* x  = (const float*)d_in[0];
    const float* Wg = (const float*)d_in[1];
    const float* bg = (const float*)d_in[2];
    const float* W0 = (const float*)d_in[3];
    const float* W1 = (const float*)d_in[4];
    const float* W2 = (const float*)d_in[5];
    const float* W3 = (const float*)d_in[6];
    const float* Wf = (const float*)d_in[7];
    float* out = (float*)d_out;

    float* h2 = (float*)d_ws;                                   // 4096*128 f32 = 2 MB
    unsigned short* W1t = (unsigned short*)((char*)d_ws + (size_t)2 * 1024 * 1024); // 256 KB
    unsigned short* W2t = W1t + (size_t)64 * 2048;                                  // 32 KB

    k_prep<<<dim3(72), dim3(256), 0, stream>>>(W1, W2, W1t, W2t);
    k_tree<<<dim3((4096 / TB) * 8), dim3(256), 0, stream>>>(x, Wg, bg, W0, W1t, W2t, h2);
    k_root<<<dim3(4096 / 8), dim3(128), 0, stream>>>(h2, W3, Wf, out);
}